// Round 1
// baseline (727.259 us; speedup 1.0000x reference)
//
#include <hip/hip_runtime.h>

#define NN 50000
#define NE 800000
#define NB 128
#define FIN 30
#define H 64
#define NC 10
#define L 3

// ---------------- kernels ----------------

__global__ __launch_bounds__(256) void embed_concat_kernel(
    const float* __restrict__ x, const int* __restrict__ ports,
    const int* __restrict__ flags, const float* __restrict__ emb_port,
    const float* __restrict__ emb_flags, float* __restrict__ h)
{
    int tid = blockIdx.x * 256 + threadIdx.x;
    int n = tid >> 6, f = tid & 63;
    if (n >= NN) return;
    float v;
    if (f < FIN)            v = x[n * FIN + f];
    else if (f < FIN + 32)  v = emb_port[ports[n] * 32 + (f - FIN)];
    else                    v = emb_flags[flags[n] * 2 + (f - FIN - 32)];
    h[n * H + f] = v;
}

__global__ __launch_bounds__(256) void hist_kernel(
    const int* __restrict__ dst, int* __restrict__ cnt)
{
    int e = blockIdx.x * 256 + threadIdx.x;
    if (e < NE) atomicAdd(&cnt[dst[e]], 1);
}

// single-block exclusive scan over NN counts -> row_start[NN+1]
__global__ __launch_bounds__(1024) void scan_kernel(
    const int* __restrict__ cnt, int* __restrict__ row_start)
{
    __shared__ int tmp[1024];
    __shared__ int carry_s;
    if (threadIdx.x == 0) { carry_s = 0; row_start[0] = 0; }
    __syncthreads();
    for (int base = 0; base < NN; base += 1024) {
        int i = base + threadIdx.x;
        int v = (i < NN) ? cnt[i] : 0;
        tmp[threadIdx.x] = v;
        __syncthreads();
        for (int off = 1; off < 1024; off <<= 1) {
            int t = (threadIdx.x >= off) ? tmp[threadIdx.x - off] : 0;
            __syncthreads();
            tmp[threadIdx.x] += t;
            __syncthreads();
        }
        int carry = carry_s;
        if (i < NN) row_start[i + 1] = carry + tmp[threadIdx.x];
        __syncthreads();
        if (threadIdx.x == 1023) carry_s = carry + tmp[1023];
        __syncthreads();
    }
}

__global__ __launch_bounds__(256) void scatter_edges_kernel(
    const int* __restrict__ src, const int* __restrict__ dst,
    const int* __restrict__ row_start, int* __restrict__ cursor,
    int* __restrict__ edge_src)
{
    int e = blockIdx.x * 256 + threadIdx.x;
    if (e >= NE) return;
    int d = dst[e];
    int pos = atomicAdd(&cursor[d], 1);
    edge_src[row_start[d] + pos] = src[e];
}

// one wave per node, lane = feature; gather-sum incoming neighbors
__global__ __launch_bounds__(256) void aggregate_kernel(
    const float* __restrict__ h, const int* __restrict__ row_start,
    const int* __restrict__ edge_src, float* __restrict__ agg)
{
    int wid = (blockIdx.x * 256 + threadIdx.x) >> 6;
    int lane = threadIdx.x & 63;
    if (wid >= NN) return;
    int p0 = row_start[wid], p1 = row_start[wid + 1];
    float acc = 0.f;
    for (int p = p0; p < p1; ++p) {
        int s = edge_src[p];
        acc += h[s * H + lane];
    }
    agg[wid * H + lane] = acc;
}

// h = relu(agg @ Wrel^T + brel + h @ Wroot^T), in place on h.
// block = 256 threads handles 64 nodes; rows staged in LDS (+1 pad).
__global__ __launch_bounds__(256) void linear_relu_kernel(
    float* __restrict__ h, const float* __restrict__ agg,
    const float* __restrict__ Wrel, const float* __restrict__ brel,
    const float* __restrict__ Wroot)
{
    __shared__ float sa[64 * 65];
    __shared__ float sh[64 * 65];
    int node0 = blockIdx.x * 64;
    for (int t = threadIdx.x; t < 64 * 64; t += 256) {
        int r = t >> 6, c = t & 63;
        int n = node0 + r;
        float va = 0.f, vh = 0.f;
        if (n < NN) { va = agg[n * H + c]; vh = h[n * H + c]; }
        sa[r * 65 + c] = va;
        sh[r * 65 + c] = vh;
    }
    __syncthreads();
    int r  = threadIdx.x & 63;          // node within tile
    int jt = (threadIdx.x >> 6) * 16;   // output chunk (wave-uniform)
    int n  = node0 + r;
    float acc[16];
#pragma unroll
    for (int j = 0; j < 16; ++j) acc[j] = brel[jt + j];
    for (int k = 0; k < 64; ++k) {
        float a  = sa[r * 65 + k];
        float hh = sh[r * 65 + k];
#pragma unroll
        for (int j = 0; j < 16; ++j) {
            acc[j] = fmaf(a, Wrel[(jt + j) * 64 + k],
                     fmaf(hh, Wroot[(jt + j) * 64 + k], acc[j]));
        }
    }
    if (n < NN) {
#pragma unroll
        for (int j = 0; j < 16; ++j)
            h[n * H + jt + j] = fmaxf(acc[j], 0.f);
    }
}

// relu output >= 0 -> int-bitwise atomicMax == float max
__global__ __launch_bounds__(256) void pool_max_kernel(
    const float* __restrict__ h, const int* __restrict__ batch,
    int* __restrict__ g_bits)
{
    int tid = blockIdx.x * 256 + threadIdx.x;
    int n = tid >> 6, f = tid & 63;
    if (n >= NN) return;
    float v = h[n * H + f];
    atomicMax(&g_bits[batch[n] * H + f], __float_as_int(v));
}

__global__ __launch_bounds__(64) void mlp_kernel(
    const int* __restrict__ g_bits,
    const float* __restrict__ fc1W, const float* __restrict__ fc1b,
    const float* __restrict__ fc2W, const float* __restrict__ fc2b,
    const float* __restrict__ fc3W, const float* __restrict__ fc3b,
    float* __restrict__ out)
{
    __shared__ float s0[64];
    __shared__ float s1[64];
    int b = blockIdx.x, j = threadIdx.x;
    s0[j] = __int_as_float(g_bits[b * H + j]);
    __syncthreads();
    float acc = fc1b[j];
    for (int k = 0; k < 64; ++k) acc = fmaf(s0[k], fc1W[j * 64 + k], acc);
    s1[j] = fmaxf(acc, 0.f);
    __syncthreads();
    acc = fc2b[j];
    for (int k = 0; k < 64; ++k) acc = fmaf(s1[k], fc2W[j * 64 + k], acc);
    __syncthreads();           // all reads of s0 finished pre-barrier above; safe to rewrite
    s0[j] = fmaxf(acc, 0.f);
    __syncthreads();
    if (j < NC) {
        acc = fc3b[j];
        for (int k = 0; k < 64; ++k) acc = fmaf(s0[k], fc3W[j * 64 + k], acc);
        out[b * NC + j] = acc;
    }
}

// ---------------- launcher ----------------

extern "C" void kernel_launch(void* const* d_in, const int* in_sizes, int n_in,
                              void* d_out, int out_size, void* d_ws, size_t ws_size,
                              hipStream_t stream)
{
    const float* x         = (const float*)d_in[0];
    const int*   dst_ports = (const int*)d_in[1];
    const int*   tcp_flags = (const int*)d_in[2];
    const int*   edge_src_in = (const int*)d_in[3];          // row 0 of (2,E)
    const int*   edge_dst_in = edge_src_in + NE;             // row 1
    const int*   batch     = (const int*)d_in[4];
    const float* emb_port  = (const float*)d_in[5];
    const float* emb_flags = (const float*)d_in[6];
    const float* Wrel      = (const float*)d_in[7];
    const float* brel      = (const float*)d_in[8];
    const float* Wroot     = (const float*)d_in[9];
    const float* fc1W      = (const float*)d_in[10];
    const float* fc1b      = (const float*)d_in[11];
    const float* fc2W      = (const float*)d_in[12];
    const float* fc2b      = (const float*)d_in[13];
    const float* fc3W      = (const float*)d_in[14];
    const float* fc3b      = (const float*)d_in[15];
    float* out = (float*)d_out;

    // workspace carve-up (256B aligned)
    char* ws = (char*)d_ws;
    size_t off = 0;
    auto alloc = [&](size_t bytes) {
        void* p = ws + off;
        off += (bytes + 255) & ~(size_t)255;
        return p;
    };
    float* h        = (float*)alloc((size_t)NN * H * 4);
    float* agg      = (float*)alloc((size_t)NN * H * 4);
    int*   cnt      = (int*)alloc((size_t)NN * 4);
    int*   row_start= (int*)alloc((size_t)(NN + 1) * 4);
    int*   cursor   = (int*)alloc((size_t)NN * 4);
    int*   edge_src = (int*)alloc((size_t)NE * 4);
    int*   g_bits   = (int*)alloc((size_t)NB * H * 4);

    // zero what needs zeroing (ws is poisoned 0xAA each call)
    hipMemsetAsync(cnt, 0, (size_t)NN * 4, stream);
    hipMemsetAsync(cursor, 0, (size_t)NN * 4, stream);
    hipMemsetAsync(g_bits, 0, (size_t)NB * H * 4, stream);

    // h0 = concat(x, emb_port[ports], emb_flags[flags])
    embed_concat_kernel<<<(NN * 64 + 255) / 256, 256, 0, stream>>>(
        x, dst_ports, tcp_flags, emb_port, emb_flags, h);

    // CSR build (by dst)
    hist_kernel<<<(NE + 255) / 256, 256, 0, stream>>>(edge_dst_in, cnt);
    scan_kernel<<<1, 1024, 0, stream>>>(cnt, row_start);
    scatter_edges_kernel<<<(NE + 255) / 256, 256, 0, stream>>>(
        edge_src_in, edge_dst_in, row_start, cursor, edge_src);

    // 3 GraphConv layers
    for (int l = 0; l < L; ++l) {
        aggregate_kernel<<<(NN + 3) / 4, 256, 0, stream>>>(h, row_start, edge_src, agg);
        linear_relu_kernel<<<(NN + 63) / 64, 256, 0, stream>>>(
            h, agg, Wrel + l * H * H, brel + l * H, Wroot + l * H * H);
    }

    // global max pool
    pool_max_kernel<<<(NN * 64 + 255) / 256, 256, 0, stream>>>(h, batch, g_bits);

    // MLP head
    mlp_kernel<<<NB, 64, 0, stream>>>(g_bits, fc1W, fc1b, fc2W, fc2b, fc3W, fc3b, out);
}

// Round 2
// 724.844 us; speedup vs baseline: 1.0033x; 1.0033x over previous
//
#include <hip/hip_runtime.h>

#define NN 50000
#define NE 800000
#define NB 128
#define FIN 30
#define H 64
#define NC 10
#define L 3

// ---------------- kernels ----------------

__global__ __launch_bounds__(256) void embed_concat_kernel(
    const float* __restrict__ x, const int* __restrict__ ports,
    const int* __restrict__ flags, const float* __restrict__ emb_port,
    const float* __restrict__ emb_flags, float* __restrict__ h)
{
    int tid = blockIdx.x * 256 + threadIdx.x;
    int n = tid >> 6, f = tid & 63;
    if (n >= NN) return;
    float v;
    if (f < FIN)            v = x[n * FIN + f];
    else if (f < FIN + 32)  v = emb_port[ports[n] * 32 + (f - FIN)];
    else                    v = emb_flags[flags[n] * 2 + (f - FIN - 32)];
    h[n * H + f] = v;
}

__global__ __launch_bounds__(256) void hist_kernel(
    const int* __restrict__ dst, int* __restrict__ cnt)
{
    int e = blockIdx.x * 256 + threadIdx.x;
    if (e < NE) atomicAdd(&cnt[dst[e]], 1);
}

// ---- hierarchical scan: 49 blocks x 1024 -> 49 block sums -> offsets ----

__global__ __launch_bounds__(1024) void scan1_kernel(
    const int* __restrict__ cnt, int* __restrict__ row_start, int* __restrict__ bsum)
{
    __shared__ int wsum[16];
    int i = blockIdx.x * 1024 + threadIdx.x;
    int lane = threadIdx.x & 63;
    int wv = threadIdx.x >> 6;
    int v = (i < NN) ? cnt[i] : 0;
    int s = v;
    for (int off = 1; off < 64; off <<= 1) {
        int t = __shfl_up(s, off);
        if (lane >= off) s += t;
    }
    if (lane == 63) wsum[wv] = s;
    __syncthreads();
    if (wv == 0) {
        int ws = (lane < 16) ? wsum[lane] : 0;
        for (int off = 1; off < 16; off <<= 1) {
            int t = __shfl_up(ws, off);
            if (lane >= off) ws += t;
        }
        if (lane < 16) wsum[lane] = ws;   // inclusive per-wave sums
    }
    __syncthreads();
    int base = (wv > 0) ? wsum[wv - 1] : 0;
    s += base;
    if (i < NN) row_start[i + 1] = s;
    if (threadIdx.x == 1023) bsum[blockIdx.x] = s;  // block total
    if (i == 0) row_start[0] = 0;
}

__global__ __launch_bounds__(64) void scan2_kernel(int* __restrict__ bsum)
{
    int lane = threadIdx.x;
    int v = (lane < 49) ? bsum[lane] : 0;
    for (int off = 1; off < 64; off <<= 1) {
        int t = __shfl_up(v, off);
        if (lane >= off) v += t;
    }
    if (lane < 49) bsum[lane] = v;        // inclusive sums
}

__global__ __launch_bounds__(1024) void scan3_kernel(
    int* __restrict__ row_start, const int* __restrict__ bsum)
{
    int b = blockIdx.x + 1;               // blocks 1..48
    int i = b * 1024 + threadIdx.x;
    if (i < NN) row_start[i + 1] += bsum[b - 1];
}

__global__ __launch_bounds__(256) void scatter_edges_kernel(
    const int* __restrict__ src, const int* __restrict__ dst,
    const int* __restrict__ row_start, int* __restrict__ cursor,
    int* __restrict__ edge_src)
{
    int e = blockIdx.x * 256 + threadIdx.x;
    if (e >= NE) return;
    int d = dst[e];
    int pos = atomicAdd(&cursor[d], 1);
    edge_src[row_start[d] + pos] = src[e];
}

// fused GraphConv layer: gather-sum + (agg@Wrel^T + brel + h@Wroot^T) + relu
// 64 nodes per block; ping-pong h_in -> h_out (no in-place race).
__global__ __launch_bounds__(256) void conv_kernel(
    const float* __restrict__ h_in, float* __restrict__ h_out,
    const int* __restrict__ row_start, const int* __restrict__ edge_src,
    const float* __restrict__ Wrel, const float* __restrict__ brel,
    const float* __restrict__ Wroot)
{
    __shared__ float sa[64 * 65];   // aggregated neighbor sums
    __shared__ float sh[64 * 65];   // self rows
    int node0 = blockIdx.x * 64;
    int lane = threadIdx.x & 63;
    int w    = threadIdx.x >> 6;

    // gather phase: wave w handles nodes w*16 .. w*16+15; lane = feature
    for (int i = 0; i < 16; ++i) {
        int r = w * 16 + i;
        int n = node0 + r;
        float self = 0.f, acc = 0.f;
        if (n < NN) {
            self = h_in[n * H + lane];
            int p0 = row_start[n], p1 = row_start[n + 1];
            for (int p = p0; p < p1; ++p)
                acc += h_in[edge_src[p] * H + lane];
        }
        sh[r * 65 + lane] = self;
        sa[r * 65 + lane] = acc;
    }
    __syncthreads();

    // linear phase: thread = (node r, output chunk jt); weights via scalar path
    int r  = lane;
    int jt = __builtin_amdgcn_readfirstlane((threadIdx.x >> 6) * 16);
    int n  = node0 + r;
    float acc[16];
#pragma unroll
    for (int j = 0; j < 16; ++j) acc[j] = brel[jt + j];
    for (int k = 0; k < 64; ++k) {
        float a  = sa[r * 65 + k];
        float hh = sh[r * 65 + k];
#pragma unroll
        for (int j = 0; j < 16; ++j) {
            acc[j] = fmaf(a, Wrel[(jt + j) * 64 + k],
                     fmaf(hh, Wroot[(jt + j) * 64 + k], acc[j]));
        }
    }
    if (n < NN) {
#pragma unroll
        for (int j = 0; j < 16; ++j)
            h_out[n * H + jt + j] = fmaxf(acc[j], 0.f);
    }
}

// relu output >= 0 -> int-bitwise atomicMax == float max
__global__ __launch_bounds__(256) void pool_max_kernel(
    const float* __restrict__ h, const int* __restrict__ batch,
    int* __restrict__ g_bits)
{
    int tid = blockIdx.x * 256 + threadIdx.x;
    int n = tid >> 6, f = tid & 63;
    if (n >= NN) return;
    float v = h[n * H + f];
    atomicMax(&g_bits[batch[n] * H + f], __float_as_int(v));
}

__global__ __launch_bounds__(64) void mlp_kernel(
    const int* __restrict__ g_bits,
    const float* __restrict__ fc1W, const float* __restrict__ fc1b,
    const float* __restrict__ fc2W, const float* __restrict__ fc2b,
    const float* __restrict__ fc3W, const float* __restrict__ fc3b,
    float* __restrict__ out)
{
    __shared__ float s0[64];
    __shared__ float s1[64];
    int b = blockIdx.x, j = threadIdx.x;
    s0[j] = __int_as_float(g_bits[b * H + j]);
    __syncthreads();
    float acc = fc1b[j];
    for (int k = 0; k < 64; ++k) acc = fmaf(s0[k], fc1W[j * 64 + k], acc);
    s1[j] = fmaxf(acc, 0.f);
    __syncthreads();
    acc = fc2b[j];
    for (int k = 0; k < 64; ++k) acc = fmaf(s1[k], fc2W[j * 64 + k], acc);
    __syncthreads();
    s0[j] = fmaxf(acc, 0.f);
    __syncthreads();
    if (j < NC) {
        acc = fc3b[j];
        for (int k = 0; k < 64; ++k) acc = fmaf(s0[k], fc3W[j * 64 + k], acc);
        out[b * NC + j] = acc;
    }
}

// ---------------- launcher ----------------

extern "C" void kernel_launch(void* const* d_in, const int* in_sizes, int n_in,
                              void* d_out, int out_size, void* d_ws, size_t ws_size,
                              hipStream_t stream)
{
    const float* x         = (const float*)d_in[0];
    const int*   dst_ports = (const int*)d_in[1];
    const int*   tcp_flags = (const int*)d_in[2];
    const int*   edge_src_in = (const int*)d_in[3];          // row 0 of (2,E)
    const int*   edge_dst_in = edge_src_in + NE;             // row 1
    const int*   batch     = (const int*)d_in[4];
    const float* emb_port  = (const float*)d_in[5];
    const float* emb_flags = (const float*)d_in[6];
    const float* Wrel      = (const float*)d_in[7];
    const float* brel      = (const float*)d_in[8];
    const float* Wroot     = (const float*)d_in[9];
    const float* fc1W      = (const float*)d_in[10];
    const float* fc1b      = (const float*)d_in[11];
    const float* fc2W      = (const float*)d_in[12];
    const float* fc2b      = (const float*)d_in[13];
    const float* fc3W      = (const float*)d_in[14];
    const float* fc3b      = (const float*)d_in[15];
    float* out = (float*)d_out;

    // workspace carve-up (256B aligned)
    char* ws = (char*)d_ws;
    size_t off = 0;
    auto alloc = [&](size_t bytes) {
        void* p = ws + off;
        off += (bytes + 255) & ~(size_t)255;
        return p;
    };
    float* h0       = (float*)alloc((size_t)NN * H * 4);
    float* h1       = (float*)alloc((size_t)NN * H * 4);
    int*   cnt      = (int*)alloc((size_t)NN * 4);
    int*   row_start= (int*)alloc((size_t)(NN + 1) * 4);
    int*   cursor   = (int*)alloc((size_t)NN * 4);
    int*   edge_src = (int*)alloc((size_t)NE * 4);
    int*   g_bits   = (int*)alloc((size_t)NB * H * 4);
    int*   bsum     = (int*)alloc((size_t)64 * 4);

    // zero what needs zeroing (ws is poisoned 0xAA each call)
    hipMemsetAsync(cnt, 0, (size_t)NN * 4, stream);
    hipMemsetAsync(cursor, 0, (size_t)NN * 4, stream);
    hipMemsetAsync(g_bits, 0, (size_t)NB * H * 4, stream);

    // h0 = concat(x, emb_port[ports], emb_flags[flags])
    embed_concat_kernel<<<(NN * 64 + 255) / 256, 256, 0, stream>>>(
        x, dst_ports, tcp_flags, emb_port, emb_flags, h0);

    // CSR build (by dst)
    hist_kernel<<<(NE + 255) / 256, 256, 0, stream>>>(edge_dst_in, cnt);
    scan1_kernel<<<(NN + 1023) / 1024, 1024, 0, stream>>>(cnt, row_start, bsum);
    scan2_kernel<<<1, 64, 0, stream>>>(bsum);
    scan3_kernel<<<(NN + 1023) / 1024 - 1, 1024, 0, stream>>>(row_start, bsum);
    scatter_edges_kernel<<<(NE + 255) / 256, 256, 0, stream>>>(
        edge_src_in, edge_dst_in, row_start, cursor, edge_src);

    // 3 fused GraphConv layers, ping-pong
    conv_kernel<<<(NN + 63) / 64, 256, 0, stream>>>(
        h0, h1, row_start, edge_src, Wrel + 0 * H * H, brel + 0 * H, Wroot + 0 * H * H);
    conv_kernel<<<(NN + 63) / 64, 256, 0, stream>>>(
        h1, h0, row_start, edge_src, Wrel + 1 * H * H, brel + 1 * H, Wroot + 1 * H * H);
    conv_kernel<<<(NN + 63) / 64, 256, 0, stream>>>(
        h0, h1, row_start, edge_src, Wrel + 2 * H * H, brel + 2 * H, Wroot + 2 * H * H);

    // global max pool (final h is h1)
    pool_max_kernel<<<(NN * 64 + 255) / 256, 256, 0, stream>>>(h1, batch, g_bits);

    // MLP head
    mlp_kernel<<<NB, 64, 0, stream>>>(g_bits, fc1W, fc1b, fc2W, fc2b, fc3W, fc3b, out);
}

// Round 3
// 430.193 us; speedup vs baseline: 1.6905x; 1.6849x over previous
//
#include <hip/hip_runtime.h>

#define NN 50000
#define NE 800000
#define NB 128
#define FIN 30
#define H 64
#define NC 10
#define L 3

// ---------------- kernels ----------------

__global__ __launch_bounds__(256) void embed_concat_kernel(
    const float* __restrict__ x, const int* __restrict__ ports,
    const int* __restrict__ flags, const float* __restrict__ emb_port,
    const float* __restrict__ emb_flags, float* __restrict__ h)
{
    int tid = blockIdx.x * 256 + threadIdx.x;
    int n = tid >> 6, f = tid & 63;
    if (n >= NN) return;
    float v;
    if (f < FIN)            v = x[n * FIN + f];
    else if (f < FIN + 32)  v = emb_port[ports[n] * 32 + (f - FIN)];
    else                    v = emb_flags[flags[n] * 2 + (f - FIN - 32)];
    h[n * H + f] = v;
}

__global__ __launch_bounds__(256) void hist_kernel(
    const int* __restrict__ dst, int* __restrict__ cnt)
{
    int e = blockIdx.x * 256 + threadIdx.x;
    if (e < NE) atomicAdd(&cnt[dst[e]], 1);
}

// ---- hierarchical scan: 49 blocks x 1024 -> 49 block sums -> offsets ----

__global__ __launch_bounds__(1024) void scan1_kernel(
    const int* __restrict__ cnt, int* __restrict__ row_start, int* __restrict__ bsum)
{
    __shared__ int wsum[16];
    int i = blockIdx.x * 1024 + threadIdx.x;
    int lane = threadIdx.x & 63;
    int wv = threadIdx.x >> 6;
    int v = (i < NN) ? cnt[i] : 0;
    int s = v;
    for (int off = 1; off < 64; off <<= 1) {
        int t = __shfl_up(s, off);
        if (lane >= off) s += t;
    }
    if (lane == 63) wsum[wv] = s;
    __syncthreads();
    if (wv == 0) {
        int ws = (lane < 16) ? wsum[lane] : 0;
        for (int off = 1; off < 16; off <<= 1) {
            int t = __shfl_up(ws, off);
            if (lane >= off) ws += t;
        }
        if (lane < 16) wsum[lane] = ws;   // inclusive per-wave sums
    }
    __syncthreads();
    int base = (wv > 0) ? wsum[wv - 1] : 0;
    s += base;
    if (i < NN) row_start[i + 1] = s;
    if (threadIdx.x == 1023) bsum[blockIdx.x] = s;  // block total
    if (i == 0) row_start[0] = 0;
}

__global__ __launch_bounds__(64) void scan2_kernel(int* __restrict__ bsum)
{
    int lane = threadIdx.x;
    int v = (lane < 49) ? bsum[lane] : 0;
    for (int off = 1; off < 64; off <<= 1) {
        int t = __shfl_up(v, off);
        if (lane >= off) v += t;
    }
    if (lane < 49) bsum[lane] = v;        // inclusive sums
}

__global__ __launch_bounds__(1024) void scan3_kernel(
    int* __restrict__ row_start, const int* __restrict__ bsum)
{
    int b = blockIdx.x + 1;               // blocks 1..48
    int i = b * 1024 + threadIdx.x;
    if (i < NN) row_start[i + 1] += bsum[b - 1];
}

__global__ __launch_bounds__(256) void scatter_edges_kernel(
    const int* __restrict__ src, const int* __restrict__ dst,
    const int* __restrict__ row_start, int* __restrict__ cursor,
    int* __restrict__ edge_src)
{
    int e = blockIdx.x * 256 + threadIdx.x;
    if (e >= NE) return;
    int d = dst[e];
    int pos = atomicAdd(&cursor[d], 1);
    edge_src[row_start[d] + pos] = src[e];
}

// fused GraphConv layer: gather-sum + (agg@Wrel^T + brel + h@Wroot^T) + relu
// 64 nodes per block; ping-pong h_in -> h_out.
// Gather: lane = (edge-slot sub 0..3, feature-quad f4 0..15); float4 loads,
// 4 edges per wave-instruction, unroll x2 -> ~8 edges in flight.
__global__ __launch_bounds__(256) void conv_kernel(
    const float* __restrict__ h_in, float* __restrict__ h_out,
    const int* __restrict__ row_start, const int* __restrict__ edge_src,
    const float* __restrict__ Wrel, const float* __restrict__ brel,
    const float* __restrict__ Wroot)
{
    __shared__ float sa[64 * 65];   // aggregated neighbor sums
    __shared__ float sh[64 * 65];   // self rows
    int node0 = blockIdx.x * 64;
    int tid  = threadIdx.x;
    int lane = tid & 63;
    int w    = tid >> 6;
    int sub  = lane >> 4;    // edge slot within wave
    int f4   = lane & 15;    // feature quad

    // cooperative coalesced self-row load: 64 rows x 16 float4
    {
        const float4* srcp = (const float4*)(h_in + (size_t)node0 * H);
        int limit = (NN - node0) * 16;          // valid float4s in tile
        for (int t = tid; t < 1024; t += 256) {
            float4 v = make_float4(0.f, 0.f, 0.f, 0.f);
            if (t < limit) v = srcp[t];
            int r = t >> 4, kq = t & 15;
            sh[r * 65 + kq * 4 + 0] = v.x;
            sh[r * 65 + kq * 4 + 1] = v.y;
            sh[r * 65 + kq * 4 + 2] = v.z;
            sh[r * 65 + kq * 4 + 3] = v.w;
        }
    }

    // gather phase: wave w handles rows w*16 .. w*16+15
    for (int i = 0; i < 16; ++i) {
        int r = w * 16 + i;
        int n = node0 + r;
        float4 a0 = make_float4(0.f, 0.f, 0.f, 0.f);
        float4 a1 = make_float4(0.f, 0.f, 0.f, 0.f);
        if (n < NN) {
            int p1 = row_start[n + 1];
            int p  = row_start[n] + sub;
            // unroll x2: two independent gather loads in flight
            for (; p + 4 < p1; p += 8) {
                int s0 = edge_src[p];
                int s1 = edge_src[p + 4];
                float4 v0 = ((const float4*)(h_in + (size_t)s0 * H))[f4];
                float4 v1 = ((const float4*)(h_in + (size_t)s1 * H))[f4];
                a0.x += v0.x; a0.y += v0.y; a0.z += v0.z; a0.w += v0.w;
                a1.x += v1.x; a1.y += v1.y; a1.z += v1.z; a1.w += v1.w;
            }
            if (p < p1) {
                int s0 = edge_src[p];
                float4 v0 = ((const float4*)(h_in + (size_t)s0 * H))[f4];
                a0.x += v0.x; a0.y += v0.y; a0.z += v0.z; a0.w += v0.w;
            }
        }
        a0.x += a1.x; a0.y += a1.y; a0.z += a1.z; a0.w += a1.w;
        // butterfly sum across the 4 edge slots
        #pragma unroll
        for (int m = 16; m < 64; m <<= 1) {
            a0.x += __shfl_xor(a0.x, m);
            a0.y += __shfl_xor(a0.y, m);
            a0.z += __shfl_xor(a0.z, m);
            a0.w += __shfl_xor(a0.w, m);
        }
        if (sub == 0) {
            sa[r * 65 + f4 * 4 + 0] = a0.x;
            sa[r * 65 + f4 * 4 + 1] = a0.y;
            sa[r * 65 + f4 * 4 + 2] = a0.z;
            sa[r * 65 + f4 * 4 + 3] = a0.w;
        }
    }
    __syncthreads();

    // linear phase: thread = (node r, output chunk jt); weights via scalar path
    int r  = lane;
    int jt = __builtin_amdgcn_readfirstlane((tid >> 6) * 16);
    int n  = node0 + r;
    float acc[16];
#pragma unroll
    for (int j = 0; j < 16; ++j) acc[j] = brel[jt + j];
    for (int k = 0; k < 64; ++k) {
        float a  = sa[r * 65 + k];
        float hh = sh[r * 65 + k];
#pragma unroll
        for (int j = 0; j < 16; ++j) {
            acc[j] = fmaf(a, Wrel[(jt + j) * 64 + k],
                     fmaf(hh, Wroot[(jt + j) * 64 + k], acc[j]));
        }
    }
    if (n < NN) {
#pragma unroll
        for (int j = 0; j < 16; ++j)
            h_out[n * H + jt + j] = fmaxf(acc[j], 0.f);
    }
}

// relu output >= 0 -> int-bitwise atomicMax == float max
__global__ __launch_bounds__(256) void pool_max_kernel(
    const float* __restrict__ h, const int* __restrict__ batch,
    int* __restrict__ g_bits)
{
    int tid = blockIdx.x * 256 + threadIdx.x;
    int n = tid >> 6, f = tid & 63;
    if (n >= NN) return;
    float v = h[n * H + f];
    atomicMax(&g_bits[batch[n] * H + f], __float_as_int(v));
}

__global__ __launch_bounds__(64) void mlp_kernel(
    const int* __restrict__ g_bits,
    const float* __restrict__ fc1W, const float* __restrict__ fc1b,
    const float* __restrict__ fc2W, const float* __restrict__ fc2b,
    const float* __restrict__ fc3W, const float* __restrict__ fc3b,
    float* __restrict__ out)
{
    __shared__ float s0[64];
    __shared__ float s1[64];
    int b = blockIdx.x, j = threadIdx.x;
    s0[j] = __int_as_float(g_bits[b * H + j]);
    __syncthreads();
    float acc = fc1b[j];
    for (int k = 0; k < 64; ++k) acc = fmaf(s0[k], fc1W[j * 64 + k], acc);
    s1[j] = fmaxf(acc, 0.f);
    __syncthreads();
    acc = fc2b[j];
    for (int k = 0; k < 64; ++k) acc = fmaf(s1[k], fc2W[j * 64 + k], acc);
    __syncthreads();
    s0[j] = fmaxf(acc, 0.f);
    __syncthreads();
    if (j < NC) {
        acc = fc3b[j];
        for (int k = 0; k < 64; ++k) acc = fmaf(s0[k], fc3W[j * 64 + k], acc);
        out[b * NC + j] = acc;
    }
}

// ---------------- launcher ----------------

extern "C" void kernel_launch(void* const* d_in, const int* in_sizes, int n_in,
                              void* d_out, int out_size, void* d_ws, size_t ws_size,
                              hipStream_t stream)
{
    const float* x         = (const float*)d_in[0];
    const int*   dst_ports = (const int*)d_in[1];
    const int*   tcp_flags = (const int*)d_in[2];
    const int*   edge_src_in = (const int*)d_in[3];          // row 0 of (2,E)
    const int*   edge_dst_in = edge_src_in + NE;             // row 1
    const int*   batch     = (const int*)d_in[4];
    const float* emb_port  = (const float*)d_in[5];
    const float* emb_flags = (const float*)d_in[6];
    const float* Wrel      = (const float*)d_in[7];
    const float* brel      = (const float*)d_in[8];
    const float* Wroot     = (const float*)d_in[9];
    const float* fc1W      = (const float*)d_in[10];
    const float* fc1b      = (const float*)d_in[11];
    const float* fc2W      = (const float*)d_in[12];
    const float* fc2b      = (const float*)d_in[13];
    const float* fc3W      = (const float*)d_in[14];
    const float* fc3b      = (const float*)d_in[15];
    float* out = (float*)d_out;

    // workspace carve-up (256B aligned)
    char* ws = (char*)d_ws;
    size_t off = 0;
    auto alloc = [&](size_t bytes) {
        void* p = ws + off;
        off += (bytes + 255) & ~(size_t)255;
        return p;
    };
    float* h0       = (float*)alloc((size_t)NN * H * 4);
    float* h1       = (float*)alloc((size_t)NN * H * 4);
    int*   cnt      = (int*)alloc((size_t)NN * 4);
    int*   row_start= (int*)alloc((size_t)(NN + 1) * 4);
    int*   cursor   = (int*)alloc((size_t)NN * 4);
    int*   edge_src = (int*)alloc((size_t)NE * 4);
    int*   g_bits   = (int*)alloc((size_t)NB * H * 4);
    int*   bsum     = (int*)alloc((size_t)64 * 4);

    // zero what needs zeroing (ws is poisoned 0xAA each call)
    hipMemsetAsync(cnt, 0, (size_t)NN * 4, stream);
    hipMemsetAsync(cursor, 0, (size_t)NN * 4, stream);
    hipMemsetAsync(g_bits, 0, (size_t)NB * H * 4, stream);

    // h0 = concat(x, emb_port[ports], emb_flags[flags])
    embed_concat_kernel<<<(NN * 64 + 255) / 256, 256, 0, stream>>>(
        x, dst_ports, tcp_flags, emb_port, emb_flags, h0);

    // CSR build (by dst)
    hist_kernel<<<(NE + 255) / 256, 256, 0, stream>>>(edge_dst_in, cnt);
    scan1_kernel<<<(NN + 1023) / 1024, 1024, 0, stream>>>(cnt, row_start, bsum);
    scan2_kernel<<<1, 64, 0, stream>>>(bsum);
    scan3_kernel<<<(NN + 1023) / 1024 - 1, 1024, 0, stream>>>(row_start, bsum);
    scatter_edges_kernel<<<(NE + 255) / 256, 256, 0, stream>>>(
        edge_src_in, edge_dst_in, row_start, cursor, edge_src);

    // 3 fused GraphConv layers, ping-pong
    conv_kernel<<<(NN + 63) / 64, 256, 0, stream>>>(
        h0, h1, row_start, edge_src, Wrel + 0 * H * H, brel + 0 * H, Wroot + 0 * H * H);
    conv_kernel<<<(NN + 63) / 64, 256, 0, stream>>>(
        h1, h0, row_start, edge_src, Wrel + 1 * H * H, brel + 1 * H, Wroot + 1 * H * H);
    conv_kernel<<<(NN + 63) / 64, 256, 0, stream>>>(
        h0, h1, row_start, edge_src, Wrel + 2 * H * H, brel + 2 * H, Wroot + 2 * H * H);

    // global max pool (final h is h1)
    pool_max_kernel<<<(NN * 64 + 255) / 256, 256, 0, stream>>>(h1, batch, g_bits);

    // MLP head
    mlp_kernel<<<NB, 64, 0, stream>>>(g_bits, fc1W, fc1b, fc2W, fc2b, fc3W, fc3b, out);
}